// Round 15
// baseline (191.714 us; speedup 1.0000x reference)
//
#include <hip/hip_runtime.h>
#include <hip/hip_bf16.h>

// out = exp(Q K^T) V, unnormalized. B=4, S=4096, D=64, fp32 in/out.
// Round 21: fold the reduction into the main kernel (last-arriver pattern).
// R19 measured e2e 96.6 with main10 just under the ~40us fill cutoff
// (back-solve: ~33-38us). The ~2.2us/tile invariant survived barriers/LDS/
// spill/occupancy/cache-pressure elimination -- stop rewriting the loop.
// Certain remaining overhead: reduce_out8 dispatch + gap + 36MB round-trip.
// Fix: split-K last-arriver reduction in the epilogue:
//   each wave stores its partial slice (unchanged), __threadfence (release),
//   lane0 atomicAdd on a per-region counter (256 counters, 1 RMW/wave);
//   the 8th arriver fences (acquire), reads all 8 slices (coalesced float4,
//   L2/L3-resident) and writes out directly. prep2 zeroes the counters
//   (stream-ordered, re-runs every graph replay).
// Loop, prep2, partial layout: byte-identical to R19 (verified).

typedef short    s16x4 __attribute__((ext_vector_type(4)));
typedef short    s16x8 __attribute__((ext_vector_type(8)));
typedef _Float16 h16x8 __attribute__((ext_vector_type(8)));
typedef float    fx4   __attribute__((ext_vector_type(4)));
typedef float    fx16  __attribute__((ext_vector_type(16)));

constexpr int S = 4096, D = 64, BN = 128;
constexpr int TILES = S / BN;                       // 32
constexpr int HALF_TILES = TILES / 2;               // 16 per kk-half
constexpr int TILE_SHORTS  = 16 * 512;              // 16KB per array per tile
constexpr int BATCH_SHORTS = TILES * TILE_SHORTS;   // 262144

__device__ __forceinline__ unsigned short f2bf(float x) {
    unsigned u = __float_as_uint(x);
    u = (u + 0x7FFFu + ((u >> 16) & 1u)) >> 16;   // RNE
    return (unsigned short)u;
}
__device__ __forceinline__ float bf2f(unsigned short h) {
    return __uint_as_float(((unsigned)h) << 16);
}
__device__ __forceinline__ unsigned short f2h(float x) {
    union { _Float16 h; unsigned short s; } u;
    u.h = (_Float16)x;
    return u.s;
}
__device__ __forceinline__ unsigned pack_bf16(float lo, float hi) {
    __hip_bfloat162 r = __float22bfloat162_rn(make_float2(lo, hi));
    union { __hip_bfloat162 b; unsigned u; } c;
    c.b = r;
    return c.u;
}
__device__ __forceinline__ float ex2(float x) {
#if __has_builtin(__builtin_amdgcn_exp2f)
    return __builtin_amdgcn_exp2f(x);
#else
    return exp2f(x);
#endif
}

// -------- prep: K -> fp16 A-frag order, V -> bf16 B-frag order (32x32x16) ---
// Also zeroes the 256 region counters (block 0).
// K chunk c = kkq*4+ks : [lane][j] = K[t*128 + kkq*32 + (lane&31)][ks*16 + (lane>>5)*8 + j]
// V chunk c = ss*2+dt  : [lane][j] = V[t*128 + ss*16 + (lane>>5)*8 + j][dt*32 + (lane&31)]
__global__ __launch_bounds__(256) void prep2(
    const float* __restrict__ k, const float* __restrict__ v,
    unsigned short* __restrict__ kf, unsigned short* __restrict__ vf,
    unsigned* __restrict__ cnt)
{
    __shared__ unsigned short tile[128 * 72];   // row stride 72 halves (pad)
    const int tid   = threadIdx.x;
    if (blockIdx.x == 0) cnt[tid] = 0;          // 256 counters, 256 threads
    const int which = blockIdx.x & 1;           // 0 = K, 1 = V
    const int t     = (blockIdx.x >> 1) & 31;
    const int b     = blockIdx.x >> 6;
    const float* src = (which ? v : k) + ((size_t)b * S + t * BN) * D;

    #pragma unroll
    for (int i = 0; i < 8; ++i) {               // coalesced: 2048 float4s/block
        int f   = i * 256 + tid;
        int row = f >> 4;
        int c4  = (f & 15) << 2;
        float4 x = *(const float4*)(src + row * D + c4);
        s16x4 o;
        if (which) o = (s16x4){(short)f2bf(x.x), (short)f2bf(x.y),
                               (short)f2bf(x.z), (short)f2bf(x.w)};
        else       o = (s16x4){(short)f2h(x.x), (short)f2h(x.y),
                               (short)f2h(x.z), (short)f2h(x.w)};
        *(s16x4*)&tile[row * 72 + c4] = o;
    }
    __syncthreads();

    const int lane = tid & 63;
    unsigned short* dst = (which ? vf : kf) + (size_t)b * BATCH_SHORTS + t * TILE_SHORTS;
    #pragma unroll
    for (int i = 0; i < 4; ++i) {
        int c = (tid >> 6) * 4 + i;             // chunk 0..15
        s16x8 o;
        if (which == 0) {
            int row = (c >> 2) * 32 + (lane & 31);
            int dc  = (c & 3) * 16 + (lane >> 5) * 8;
            o = *(const s16x8*)&tile[row * 72 + dc];     // b128, aligned
        } else {
            int r0 = (c >> 1) * 16 + (lane >> 5) * 8;
            int dc = (c & 1) * 32 + (lane & 31);
            #pragma unroll
            for (int j = 0; j < 8; ++j) o[j] = (short)tile[(r0 + j) * 72 + dc];
        }
        *(s16x8*)(dst + c * 512 + lane * 8) = o;         // coalesced b128
    }
}

// -------- main: 8-wave cache-broadcast blocks + last-arriver reduce -------
// 256 blocks x 512 thr. All 8 waves of a block: SAME (b,kh,kkq) kk-slice,
// DIFFERENT 64-row q-groups. Identical kf/vf addresses across waves -> L1
// broadcast. No LDS, no barriers in the loop (R19-verified).
__global__ __launch_bounds__(512) void attn_main11(
    const float* __restrict__ q, const unsigned short* __restrict__ kf,
    const unsigned short* __restrict__ vf, float* __restrict__ partial,
    unsigned* __restrict__ cnt, float* __restrict__ out)
{
    const int tid = threadIdx.x, lane = tid & 63, w = tid >> 6;   // w 0..7
    const int h = lane >> 5, m5 = lane & 31;
    const int bid = blockIdx.x;
    const int kslice = bid & 7;                 // -> XCD pin (%8 round-robin)
    const int kh = kslice >> 2;                 // kk-half 0/1
    const int kkq = kslice & 3;                 // kk-quarter within tile
    const int rest = bid >> 3;                  // 0..31 = qg*4 + b
    const int b = rest & 3;                     // batch 0..3
    const int q0 = (rest >> 2) * 512 + w * 64;  // this wave's 64 q-rows
    const int t0 = kh * HALF_TILES;

    // Per-wave fragment base: chunks kkq*4 .. kkq*4+3, this lane's 16B.
    // IDENTICAL across the block's 8 waves -> L1-served broadcast.
    const unsigned short* kwb = kf + (size_t)b * BATCH_SHORTS + kkq * 4 * 512 + lane * 8;
    const unsigned short* vwb = vf + (size_t)b * BATCH_SHORTS + kkq * 4 * 512 + lane * 8;

    // Q B-frags fp16, pre-scaled by log2(e) so exp(s) = exp2(s').
    const float LOG2E = 1.4426950408889634f;
    h16x8 qf[2][4];   // [mt][ks]
    #pragma unroll
    for (int mt = 0; mt < 2; ++mt) {
        const float* qrow = q + ((size_t)b * S + q0 + mt * 32 + m5) * D + h * 8;
        #pragma unroll
        for (int ks = 0; ks < 4; ++ks) {
            float4 a = *(const float4*)(qrow + ks * 16);
            float4 c = *(const float4*)(qrow + ks * 16 + 4);
            qf[mt][ks] = (h16x8){
                (_Float16)(a.x * LOG2E), (_Float16)(a.y * LOG2E),
                (_Float16)(a.z * LOG2E), (_Float16)(a.w * LOG2E),
                (_Float16)(c.x * LOG2E), (_Float16)(c.y * LOG2E),
                (_Float16)(c.z * LOG2E), (_Float16)(c.w * LOG2E)};
        }
    }

    fx16 oacc[2][2] = {};   // [mt][dt]

    // Register double-buffer (named arrays; all indices compile-time).
    h16x8 kA0[4], kA1[4];
    s16x8 vB0[4], vB1[4];

    auto loadKV = [&](int t, h16x8* kA, s16x8* vB) {
        const unsigned short* kt = kwb + (size_t)t * TILE_SHORTS;
        const unsigned short* vt = vwb + (size_t)t * TILE_SHORTS;
        #pragma unroll
        for (int c = 0; c < 4; ++c) {
            kA[c] = *(const h16x8*)(kt + c * 512);   // global_load_dwordx4
            vB[c] = *(const s16x8*)(vt + c * 512);
        }
    };

    auto computeTile = [&](const h16x8* kA, const s16x8* vB) {
        // ---- GEMM1 (fp16 32x32x16): Sc^T[kk 32][m 32] x2 mt, d=64 ----
        fx16 sa[2] = {};
        #pragma unroll
        for (int ks = 0; ks < 4; ++ks)
            #pragma unroll
            for (int mt = 0; mt < 2; ++mt)
                sa[mt] = __builtin_amdgcn_mfma_f32_32x32x16_f16(kA[ks], qf[mt][ks], sa[mt], 0, 0, 0);

        // ---- P = exp2(Sc^T') in regs, bf16-pair packed ----
        unsigned p01[2][8];
        #pragma unroll
        for (int mt = 0; mt < 2; ++mt)
            #pragma unroll
            for (int rp = 0; rp < 8; ++rp)
                p01[mt][rp] = pack_bf16(ex2(sa[mt][2 * rp]), ex2(sa[mt][2 * rp + 1]));

        // ---- C-layout -> GEMM2 A-layout: cross-half exchange ----
        union frag { unsigned u[4]; s16x8 v; };
        frag A[2][2];   // [mt][u]
        #pragma unroll
        for (int mt = 0; mt < 2; ++mt) {
#if __has_builtin(__builtin_amdgcn_permlane32_swap)
            typedef unsigned uix2 __attribute__((ext_vector_type(2)));
            uix2 r0 = __builtin_amdgcn_permlane32_swap(p01[mt][0], p01[mt][2], false, false);
            uix2 r1 = __builtin_amdgcn_permlane32_swap(p01[mt][1], p01[mt][3], false, false);
            A[mt][0].u[0] = r0.x; A[mt][0].u[1] = r1.x;
            A[mt][0].u[2] = r0.y; A[mt][0].u[3] = r1.y;
            uix2 r2 = __builtin_amdgcn_permlane32_swap(p01[mt][4], p01[mt][6], false, false);
            uix2 r3 = __builtin_amdgcn_permlane32_swap(p01[mt][5], p01[mt][7], false, false);
            A[mt][1].u[0] = r2.x; A[mt][1].u[1] = r3.x;
            A[mt][1].u[2] = r2.y; A[mt][1].u[3] = r3.y;
#else
            unsigned sw[8];
            #pragma unroll
            for (int rp = 0; rp < 8; ++rp)
                sw[rp] = (unsigned)__shfl_xor((int)p01[mt][rp], 32, 64);
            A[mt][0].u[0] = h ? sw[2]        : p01[mt][0];
            A[mt][0].u[1] = h ? sw[3]        : p01[mt][1];
            A[mt][0].u[2] = h ? p01[mt][2]   : sw[0];
            A[mt][0].u[3] = h ? p01[mt][3]   : sw[1];
            A[mt][1].u[0] = h ? sw[6]        : p01[mt][4];
            A[mt][1].u[1] = h ? sw[7]        : p01[mt][5];
            A[mt][1].u[2] = h ? p01[mt][6]   : sw[4];
            A[mt][1].u[3] = h ? p01[mt][7]   : sw[5];
#endif
        }

        // ---- GEMM2 (bf16 32x32x16): O += P*V over this wave's 32 kk ----
        // V frag for (u,dt) = vB[u*2+dt]  (global chunk kkq*4+u*2+dt).
        #pragma unroll
        for (int u = 0; u < 2; ++u)
            #pragma unroll
            for (int dt = 0; dt < 2; ++dt)
                #pragma unroll
                for (int mt = 0; mt < 2; ++mt)
                    oacc[mt][dt] = __builtin_amdgcn_mfma_f32_32x32x16_bf16(
                        A[mt][u].v, vB[u * 2 + dt], oacc[mt][dt], 0, 0, 0);
    };

    loadKV(t0, kA0, vB0);
    // Unrolled-by-2 ping-pong: prefetch i+1 into the idle buffer while
    // computing i; compiler inserts fine-grained vmcnt via register deps.
    for (int i = 0; i < HALF_TILES; i += 2) {
        if (i + 1 < HALF_TILES) loadKV(t0 + i + 1, kA1, vB1);
        computeTile(kA0, vB0);
        if (i + 2 < HALF_TILES) loadKV(t0 + i + 2, kA0, vB0);
        computeTile(kA1, vB1);
    }

    // ---- epilogue 1: streaming store of this wave's 64x64 partial slice.
    //      partial copy index = kslice (== kh*4+kkq), 8 disjoint copies. ----
    float* pout = partial + ((size_t)kslice * 4 + b) * S * D;
    #pragma unroll
    for (int dt = 0; dt < 2; ++dt)
        #pragma unroll
        for (int mt = 0; mt < 2; ++mt)
            #pragma unroll
            for (int r = 0; r < 16; ++r) {
                int row = q0 + mt * 32 + (r & 3) + 8 * (r >> 2) + 4 * h;
                pout[(size_t)row * D + dt * 32 + m5] = oacc[mt][dt][r];
            }

    // ---- epilogue 2: last-arriver reduction. Release my stores, count in;
    //      the 8th wave for this (b, q0) region sums all 8 slices -> out. ----
    __threadfence();                                  // release partial stores
    const int region = ((q0 >> 6) << 2) + b;          // 0..255
    unsigned old = 0;
    if (lane == 0) old = atomicAdd(&cnt[region], 1u);
    old = (unsigned)__shfl((int)old, 0, 64);
    if (old == 7u) {
        __threadfence();                              // acquire others' stores
        const size_t roff = ((size_t)b * S + q0) * D / 4;      // float4 index
        const size_t cstride = (size_t)4 * S * D / 4;          // copy stride
        const float4* pb = (const float4*)partial;
        float4* og = (float4*)out;
        for (int i = lane; i < 1024; i += 64) {       // 64 rows x 64 cols
            float4 s = pb[roff + i];
            #pragma unroll
            for (int j = 1; j < 8; ++j) {
                float4 x = pb[(size_t)j * cstride + roff + i];
                s.x += x.x; s.y += x.y; s.z += x.z; s.w += x.w;
            }
            og[roff + i] = s;
        }
    }
}

// ---------------- fallback (known-good round-2 kernel) ----------------
__global__ __launch_bounds__(1024) void attn_fallback(
    const float* __restrict__ q, const float* __restrict__ k,
    const float* __restrict__ v, float* __restrict__ out)
{
    __shared__ unsigned short Kh[64][72];
    __shared__ unsigned short Kl[64][72];
    __shared__ unsigned short Vt[64][68];
    __shared__ unsigned short Pf[64][72];

    const int tid = threadIdx.x, lane = tid & 63, wave = tid >> 6;
    const int quad = lane >> 4, tq = lane & 15;
    const int kkb = wave & 3, mba = wave >> 2;
    const int b = blockIdx.y, q0 = blockIdx.x * 64;
    const float* qb = q + (size_t)b * S * D;
    const float* kb = k + (size_t)b * S * D;
    const float* vb = v + (size_t)b * S * D;
    float* ob = out + (size_t)b * S * D;

    s16x8 qh[2], ql[2];
    {
        const float* qrow = qb + (size_t)(q0 + mba * 16 + tq) * D;
        #pragma unroll
        for (int ks = 0; ks < 2; ++ks) {
            const float* src = qrow + ks * 32 + quad * 8;
            float4 f0 = *(const float4*)src;
            float4 f1 = *(const float4*)(src + 4);
            float f[8] = {f0.x, f0.y, f0.z, f0.w, f1.x, f1.y, f1.z, f1.w};
            #pragma unroll
            for (int j = 0; j < 8; ++j) {
                unsigned short hh = f2bf(f[j]);
                qh[ks][j] = (short)hh;
                ql[ks][j] = (short)f2bf(f[j] - bf2f(hh));
            }
        }
    }
    fx4 oacc = {0.f, 0.f, 0.f, 0.f};
    const int krow = tid >> 4, kc4 = (tid & 15) << 2;
    const int vd = tid & 63, vk = (tid >> 6) << 2;

    for (int t = 0; t < S / 64; ++t) {
        __syncthreads();
        const float* kt = kb + (size_t)(t * 64 + krow) * D;
        const float* vt = vb + (size_t)(t * 64 + vk) * D;
        {
            float4 kv = *(const float4*)(kt + kc4);
            unsigned short h0 = f2bf(kv.x), h1 = f2bf(kv.y), h2 = f2bf(kv.z), h3 = f2bf(kv.w);
            s16x4 a = {(short)h0, (short)h1, (short)h2, (short)h3};
            s16x4 l4 = {(short)f2bf(kv.x - bf2f(h0)), (short)f2bf(kv.y - bf2f(h1)),
                        (short)f2bf(kv.z - bf2f(h2)), (short)f2bf(kv.w - bf2f(h3))};
            *(s16x4*)&Kh[krow][kc4] = a;
            *(s16x4*)&Kl[krow][kc4] = l4;
            const float* vs = vt + vd;
            s16x4 vv = {(short)f2bf(vs[0]), (short)f2bf(vs[D]),
                        (short)f2bf(vs[2 * D]), (short)f2bf(vs[3 * D])};
            *(s16x4*)&Vt[vd][vk] = vv;
        }
        __syncthreads();
        fx4 sacc = {0.f, 0.f, 0.f, 0.f};
        #pragma unroll
        for (int ks = 0; ks < 2; ++ks) {
            s16x8 kah = *(const s16x8*)&Kh[kkb * 16 + tq][ks * 32 + quad * 8];
            s16x8 kal = *(const s16x8*)&Kl[kkb * 16 + tq][ks * 32 + quad * 8];
            sacc = __builtin_amdgcn_mfma_f32_16x16x32_bf16(kah, qh[ks], sacc, 0, 0, 0);
            sacc = __builtin_amdgcn_mfma_f32_16x16x32_bf16(kah, ql[ks], sacc, 0, 0, 0);
            sacc = __builtin_amdgcn_mfma_f32_16x16x32_bf16(kal, qh[ks], sacc, 0, 0, 0);
        }
        s16x4 pp = {(short)f2bf(__expf(sacc[0])), (short)f2bf(__expf(sacc[1])),
                    (short)f2bf(__expf(sacc[2])), (short)f2bf(__expf(sacc[3]))};
        *(s16x4*)&Pf[mba * 16 + tq][kkb * 16 + (quad << 2)] = pp;
        __syncthreads();
        #pragma unroll
        for (int ks = 0; ks < 2; ++ks) {
            s16x8 pa = *(const s16x8*)&Pf[mba * 16 + tq][ks * 32 + quad * 8];
            const unsigned short* vr = &Vt[kkb * 16 + tq][ks * 32 + quad * 8];
            s16x4 va = *(const s16x4*)vr;
            s16x4 vb2 = *(const s16x4*)(vr + 4);
            s16x8 vfull = __builtin_shufflevector(va, vb2, 0, 1, 2, 3, 4, 5, 6, 7);
            oacc = __builtin_amdgcn_mfma_f32_16x16x32_bf16(pa, vfull, oacc, 0, 0, 0);
        }
    }
    #pragma unroll
    for (int r = 0; r < 4; ++r)
        ob[(size_t)(q0 + mba * 16 + quad * 4 + r) * D + kkb * 16 + tq] = oacc[r];
}

extern "C" void kernel_launch(void* const* d_in, const int* in_sizes, int n_in,
                              void* d_out, int out_size, void* d_ws, size_t ws_size,
                              hipStream_t stream) {
    const float* q = (const float*)d_in[0];
    const float* k = (const float*)d_in[1];
    const float* v = (const float*)d_in[2];
    float* out = (float*)d_out;
    const int nbatch = in_sizes[0] / (S * D);   // 4
    const size_t elems = (size_t)nbatch * S * D;

    // ws: kf (fp16, 2MB) | vf (bf16, 2MB) | partial[8] (fp32, 32MB) | cnt 1KB
    const size_t need = elems * 2 * 2 + elems * 8 * 4 + 256 * 4;
    if (nbatch == 4 && ws_size >= need && d_ws != nullptr) {
        unsigned short* kf = (unsigned short*)d_ws;
        unsigned short* vf = kf + elems;
        float* partial = (float*)(vf + elems);
        unsigned* cnt = (unsigned*)(partial + 8 * elems);

        prep2<<<nbatch * TILES * 2, 256, 0, stream>>>(k, v, kf, vf, cnt);
        attn_main11<<<256, 512, 0, stream>>>(q, kf, vf, partial, cnt, out);
    } else {
        dim3 grid(S / 64, nbatch);
        attn_fallback<<<grid, 1024, 0, stream>>>(q, k, v, out);
    }
}

// Round 16
// 92.131 us; speedup vs baseline: 2.0809x; 2.0809x over previous
//
#include <hip/hip_runtime.h>
#include <hip/hip_bf16.h>

// out = exp(Q K^T) V, unnormalized. B=4, S=4096, D=64, fp32 in/out.
// Round 22: REVERT to the verified-best structure (91.9us harness-verified;
// 93.7 in-session). Session post-mortem:
//  * R21's in-kernel last-arriver reduce: __threadfence per wave = cross-XCD
//    L2 writeback/invalidate on gfx950 (G16) -> 2048 serialized flushes,
//    156us. Dispatch boundaries ARE the cheap global fence; keep reduce_out.
//  * 15 structural variants (atomics, coop-fuse, occupancy x4, BQ=256,
//    barrier-free, registers-direct, cache-broadcast) all measured worse or
//    neutral. Counters localize the residual to (a) a ~44us harness fill
//    inside the timed window, (b) a ~2.2us/tile latency floor invariant to
//    sync structure, LDS use, spill, occupancy, and cache pressure.
// Structure: prep2 (K->fp16 A-frags, V->bf16 B-frags) -> attn_main4
// (grid(32,4,2), 8 waves, 64KB double-buffer, vmcnt(0)+1 barrier/iter,
// permlane32_swap C->A transpose, exp2 with log2(e)-prescaled Q) ->
// reduce_out (partial[0]+partial[1], bit-exact).

typedef short    s16x4 __attribute__((ext_vector_type(4)));
typedef short    s16x8 __attribute__((ext_vector_type(8)));
typedef _Float16 h16x8 __attribute__((ext_vector_type(8)));
typedef float    fx4   __attribute__((ext_vector_type(4)));
typedef float    fx16  __attribute__((ext_vector_type(16)));

constexpr int S = 4096, D = 64, BN = 128;
constexpr int QROWS = 128;                          // q-rows per block (main4)
constexpr int TILES = S / BN;                       // 32
constexpr int HALF_TILES = TILES / 2;               // 16 per kk-half
constexpr int TILE_SHORTS  = 16 * 512;              // 16KB per array per tile
constexpr int BATCH_SHORTS = TILES * TILE_SHORTS;   // 262144

__device__ __forceinline__ unsigned short f2bf(float x) {
    unsigned u = __float_as_uint(x);
    u = (u + 0x7FFFu + ((u >> 16) & 1u)) >> 16;   // RNE
    return (unsigned short)u;
}
__device__ __forceinline__ float bf2f(unsigned short h) {
    return __uint_as_float(((unsigned)h) << 16);
}
__device__ __forceinline__ unsigned short f2h(float x) {
    union { _Float16 h; unsigned short s; } u;
    u.h = (_Float16)x;
    return u.s;
}
__device__ __forceinline__ unsigned pack_bf16(float lo, float hi) {
    __hip_bfloat162 r = __float22bfloat162_rn(make_float2(lo, hi));
    union { __hip_bfloat162 b; unsigned u; } c;
    c.b = r;
    return c.u;
}
__device__ __forceinline__ float ex2(float x) {
#if __has_builtin(__builtin_amdgcn_exp2f)
    return __builtin_amdgcn_exp2f(x);
#else
    return exp2f(x);
#endif
}

// -------- prep: K -> fp16 A-frag order, V -> bf16 B-frag order (32x32x16) ---
// K chunk c = kkq*4+ks : [lane][j] = K[t*128 + kkq*32 + (lane&31)][ks*16 + (lane>>5)*8 + j]
// V chunk c = ss*2+dt  : [lane][j] = V[t*128 + ss*16 + (lane>>5)*8 + j][dt*32 + (lane&31)]
__global__ __launch_bounds__(256) void prep2(
    const float* __restrict__ k, const float* __restrict__ v,
    unsigned short* __restrict__ kf, unsigned short* __restrict__ vf)
{
    __shared__ unsigned short tile[128 * 72];   // row stride 72 halves (pad)
    const int tid   = threadIdx.x;
    const int which = blockIdx.x & 1;           // 0 = K, 1 = V
    const int t     = (blockIdx.x >> 1) & 31;
    const int b     = blockIdx.x >> 6;
    const float* src = (which ? v : k) + ((size_t)b * S + t * BN) * D;

    #pragma unroll
    for (int i = 0; i < 8; ++i) {               // coalesced: 2048 float4s/block
        int f   = i * 256 + tid;
        int row = f >> 4;
        int c4  = (f & 15) << 2;
        float4 x = *(const float4*)(src + row * D + c4);
        s16x4 o;
        if (which) o = (s16x4){(short)f2bf(x.x), (short)f2bf(x.y),
                               (short)f2bf(x.z), (short)f2bf(x.w)};
        else       o = (s16x4){(short)f2h(x.x), (short)f2h(x.y),
                               (short)f2h(x.z), (short)f2h(x.w)};
        *(s16x4*)&tile[row * 72 + c4] = o;
    }
    __syncthreads();

    const int lane = tid & 63;
    unsigned short* dst = (which ? vf : kf) + (size_t)b * BATCH_SHORTS + t * TILE_SHORTS;
    #pragma unroll
    for (int i = 0; i < 4; ++i) {
        int c = (tid >> 6) * 4 + i;             // chunk 0..15
        s16x8 o;
        if (which == 0) {
            int row = (c >> 2) * 32 + (lane & 31);
            int dc  = (c & 3) * 16 + (lane >> 5) * 8;
            o = *(const s16x8*)&tile[row * 72 + dc];     // b128, aligned
        } else {
            int r0 = (c >> 1) * 16 + (lane >> 5) * 8;
            int dc = (c & 1) * 32 + (lane & 31);
            #pragma unroll
            for (int j = 0; j < 8; ++j) o[j] = (short)tile[(r0 + j) * 72 + dc];
        }
        *(s16x8*)(dst + c * 512 + lane * 8) = o;         // coalesced b128
    }
}

// ---------------- main: 128 q-rows per block, one kk-half per block --------
__global__ __launch_bounds__(512, 2) void attn_main4(
    const float* __restrict__ q, const unsigned short* __restrict__ kf,
    const unsigned short* __restrict__ vf, float* __restrict__ partial)
{
    __shared__ unsigned short smem[2 * 2 * TILE_SHORTS];   // 64KB: 2 x (K 16K | V 16K)

    const int tid = threadIdx.x, lane = tid & 63, w = tid >> 6;
    const int h = lane >> 5, m5 = lane & 31;
    const int mh = w & 1, kkq = w >> 1;         // m-half (64 rows), kk-quarter
    const int b = blockIdx.y, q0 = blockIdx.x * QROWS;
    const int kh = blockIdx.z;                  // kk-half 0/1
    const int t0 = kh * HALF_TILES;

    const unsigned short* kfb = kf + (size_t)b * BATCH_SHORTS;
    const unsigned short* vfb = vf + (size_t)b * BATCH_SHORTS;

    // Q B-frags fp16, pre-scaled by log2(e) so exp(s) = exp2(s').
    // B[k=h*8+j][n=m5] = log2e * Q[q0+mh*64+mt*32+m5][ks*16+h*8+j]
    const float LOG2E = 1.4426950408889634f;
    h16x8 qf[2][4];   // [mt][ks]
    #pragma unroll
    for (int mt = 0; mt < 2; ++mt) {
        const float* qrow = q + ((size_t)b * S + q0 + mh * 64 + mt * 32 + m5) * D + h * 8;
        #pragma unroll
        for (int ks = 0; ks < 4; ++ks) {
            float4 a = *(const float4*)(qrow + ks * 16);
            float4 c = *(const float4*)(qrow + ks * 16 + 4);
            qf[mt][ks] = (h16x8){
                (_Float16)(a.x * LOG2E), (_Float16)(a.y * LOG2E),
                (_Float16)(a.z * LOG2E), (_Float16)(a.w * LOG2E),
                (_Float16)(c.x * LOG2E), (_Float16)(c.y * LOG2E),
                (_Float16)(c.z * LOG2E), (_Float16)(c.w * LOG2E)};
        }
    }

    fx16 oacc[2][2] = {};   // [mt][dt], partial over (kk-quarter, kk-half)

    auto issue = [&](int t, int bi) {
        unsigned short* base = &smem[bi * 2 * TILE_SHORTS];
        #pragma unroll
        for (int ii = 0; ii < 4; ++ii) {                 // ii<2: K, else V
            int c = (ii & 1) * 8 + w;                    // chunk 0..15
            const unsigned short* g = (ii < 2 ? kfb : vfb)
                + (size_t)t * TILE_SHORTS + c * 512 + lane * 8;
            unsigned short* l = base + (ii < 2 ? 0 : TILE_SHORTS) + c * 512 + lane * 8;
            __builtin_amdgcn_global_load_lds(
                (const __attribute__((address_space(1))) unsigned int*)g,
                (__attribute__((address_space(3))) unsigned int*)l, 16, 0, 0);
        }
    };

    issue(t0, 0);

    for (int i = 0; i < HALF_TILES; ++i) {
        const int bi = i & 1;
        // Wave's 4 DMAs of tile i (issued a full iteration ago) landed; the
        // barrier proves all waves finished reading buffer bi^1 last iter.
        __asm__ volatile("" ::: "memory");
        __builtin_amdgcn_s_waitcnt(0x0F70);   // vmcnt(0), lgkm/exp untouched
        __builtin_amdgcn_s_barrier();
        __asm__ volatile("" ::: "memory");
        if (i + 1 < HALF_TILES) issue(t0 + i + 1, bi ^ 1);

        const unsigned short* kb = &smem[bi * 2 * TILE_SHORTS];
        const unsigned short* vb = kb + TILE_SHORTS;

        // ---- GEMM1 (fp16 32x32x16): Sc^T[kk 32][m 32] x2 mt, d=64 ----
        // Each K A-frag read feeds 2 MFMAs (both m-tiles).
        fx16 sa[2] = {};
        #pragma unroll
        for (int ks = 0; ks < 4; ++ks) {
            h16x8 a = *(const h16x8*)(kb + (kkq * 4 + ks) * 512 + lane * 8);
            #pragma unroll
            for (int mt = 0; mt < 2; ++mt)
                sa[mt] = __builtin_amdgcn_mfma_f32_32x32x16_f16(a, qf[mt][ks], sa[mt], 0, 0, 0);
        }

        // ---- P = exp2(Sc^T') in regs, bf16-pair packed ----
        // C-layout: kk = (r&3) + 8*(r>>2) + 4*h, m = m5. Pair rp packs regs
        // {2rp, 2rp+1}.
        unsigned p01[2][8];
        #pragma unroll
        for (int mt = 0; mt < 2; ++mt)
            #pragma unroll
            for (int rp = 0; rp < 8; ++rp)
                p01[mt][rp] = pack_bf16(ex2(sa[mt][2 * rp]), ex2(sa[mt][2 * rp + 1]));

        // ---- C-layout -> GEMM2 A-layout: cross-half exchange ----
        union frag { unsigned u[4]; s16x8 v; };
        frag A[2][2];   // [mt][u]
        #pragma unroll
        for (int mt = 0; mt < 2; ++mt) {
#if __has_builtin(__builtin_amdgcn_permlane32_swap)
            typedef unsigned uix2 __attribute__((ext_vector_type(2)));
            uix2 r0 = __builtin_amdgcn_permlane32_swap(p01[mt][0], p01[mt][2], false, false);
            uix2 r1 = __builtin_amdgcn_permlane32_swap(p01[mt][1], p01[mt][3], false, false);
            A[mt][0].u[0] = r0.x; A[mt][0].u[1] = r1.x;
            A[mt][0].u[2] = r0.y; A[mt][0].u[3] = r1.y;
            uix2 r2 = __builtin_amdgcn_permlane32_swap(p01[mt][4], p01[mt][6], false, false);
            uix2 r3 = __builtin_amdgcn_permlane32_swap(p01[mt][5], p01[mt][7], false, false);
            A[mt][1].u[0] = r2.x; A[mt][1].u[1] = r3.x;
            A[mt][1].u[2] = r2.y; A[mt][1].u[3] = r3.y;
#else
            unsigned sw[8];
            #pragma unroll
            for (int rp = 0; rp < 8; ++rp)
                sw[rp] = (unsigned)__shfl_xor((int)p01[mt][rp], 32, 64);
            A[mt][0].u[0] = h ? sw[2]        : p01[mt][0];
            A[mt][0].u[1] = h ? sw[3]        : p01[mt][1];
            A[mt][0].u[2] = h ? p01[mt][2]   : sw[0];
            A[mt][0].u[3] = h ? p01[mt][3]   : sw[1];
            A[mt][1].u[0] = h ? sw[6]        : p01[mt][4];
            A[mt][1].u[1] = h ? sw[7]        : p01[mt][5];
            A[mt][1].u[2] = h ? p01[mt][6]   : sw[4];
            A[mt][1].u[3] = h ? p01[mt][7]   : sw[5];
#endif
        }

        // ---- GEMM2 (bf16 32x32x16): O += P*V over this wave's 32 kk ----
        // Each V B-frag read feeds 2 MFMAs (both m-tiles).
        #pragma unroll
        for (int u = 0; u < 2; ++u) {
            int ss = kkq * 2 + u;                        // 16-kk step in tile
            #pragma unroll
            for (int dt = 0; dt < 2; ++dt) {
                s16x8 vv = *(const s16x8*)(vb + (ss * 2 + dt) * 512 + lane * 8);
                #pragma unroll
                for (int mt = 0; mt < 2; ++mt)
                    oacc[mt][dt] = __builtin_amdgcn_mfma_f32_32x32x16_bf16(
                        A[mt][u].v, vv, oacc[mt][dt], 0, 0, 0);
            }
        }
    }

    // ---- epilogue: reduce 4 kk-quarters per m-half; 2 dt rounds (48KB) ----
    __syncthreads();                     // all DMA drained
    float* scratch = (float*)smem;
    float* pout = partial + ((size_t)kh * gridDim.y + b) * S * D;
    #pragma unroll
    for (int dt = 0; dt < 2; ++dt) {
        if (kkq > 0) {
            float* dst = scratch + (size_t)(mh * 3 + (kkq - 1)) * 2048;
            #pragma unroll
            for (int mt = 0; mt < 2; ++mt)
                #pragma unroll
                for (int r = 0; r < 16; ++r)
                    dst[(mt * 16 + r) * 64 + lane] = oacc[mt][dt][r];
        }
        __syncthreads();
        if (kkq == 0) {
            #pragma unroll
            for (int mt = 0; mt < 2; ++mt)
                #pragma unroll
                for (int r = 0; r < 16; ++r) {
                    float val = oacc[mt][dt][r];
                    #pragma unroll
                    for (int p = 0; p < 3; ++p)
                        val += scratch[(size_t)(mh * 3 + p) * 2048 + (mt * 16 + r) * 64 + lane];
                    int row = q0 + mh * 64 + mt * 32 + (r & 3) + 8 * (r >> 2) + 4 * h;
                    pout[(size_t)row * D + dt * 32 + m5] = val;
                }
        }
        __syncthreads();
    }
}

// ---------------- final reduce: out = partial[0] + partial[1] ----------------
__global__ __launch_bounds__(256) void reduce_out(
    const float4* __restrict__ p0, const float4* __restrict__ p1,
    float4* __restrict__ o, int n4)
{
    int i = blockIdx.x * 256 + threadIdx.x;
    if (i < n4) {
        float4 a = p0[i], b = p1[i];
        o[i] = make_float4(a.x + b.x, a.y + b.y, a.z + b.z, a.w + b.w);
    }
}

// ---------------- fallback (known-good round-2 kernel) ----------------
__global__ __launch_bounds__(1024) void attn_fallback(
    const float* __restrict__ q, const float* __restrict__ k,
    const float* __restrict__ v, float* __restrict__ out)
{
    __shared__ unsigned short Kh[64][72];
    __shared__ unsigned short Kl[64][72];
    __shared__ unsigned short Vt[64][68];
    __shared__ unsigned short Pf[64][72];

    const int tid = threadIdx.x, lane = tid & 63, wave = tid >> 6;
    const int quad = lane >> 4, tq = lane & 15;
    const int kkb = wave & 3, mba = wave >> 2;
    const int b = blockIdx.y, q0 = blockIdx.x * 64;
    const float* qb = q + (size_t)b * S * D;
    const float* kb = k + (size_t)b * S * D;
    const float* vb = v + (size_t)b * S * D;
    float* ob = out + (size_t)b * S * D;

    s16x8 qh[2], ql[2];
    {
        const float* qrow = qb + (size_t)(q0 + mba * 16 + tq) * D;
        #pragma unroll
        for (int ks = 0; ks < 2; ++ks) {
            const float* src = qrow + ks * 32 + quad * 8;
            float4 f0 = *(const float4*)src;
            float4 f1 = *(const float4*)(src + 4);
            float f[8] = {f0.x, f0.y, f0.z, f0.w, f1.x, f1.y, f1.z, f1.w};
            #pragma unroll
            for (int j = 0; j < 8; ++j) {
                unsigned short hh = f2bf(f[j]);
                qh[ks][j] = (short)hh;
                ql[ks][j] = (short)f2bf(f[j] - bf2f(hh));
            }
        }
    }
    fx4 oacc = {0.f, 0.f, 0.f, 0.f};
    const int krow = tid >> 4, kc4 = (tid & 15) << 2;
    const int vd = tid & 63, vk = (tid >> 6) << 2;

    for (int t = 0; t < S / 64; ++t) {
        __syncthreads();
        const float* kt = kb + (size_t)(t * 64 + krow) * D;
        const float* vt = vb + (size_t)(t * 64 + vk) * D;
        {
            float4 kv = *(const float4*)(kt + kc4);
            unsigned short h0 = f2bf(kv.x), h1 = f2bf(kv.y), h2 = f2bf(kv.z), h3 = f2bf(kv.w);
            s16x4 a = {(short)h0, (short)h1, (short)h2, (short)h3};
            s16x4 l4 = {(short)f2bf(kv.x - bf2f(h0)), (short)f2bf(kv.y - bf2f(h1)),
                        (short)f2bf(kv.z - bf2f(h2)), (short)f2bf(kv.w - bf2f(h3))};
            *(s16x4*)&Kh[krow][kc4] = a;
            *(s16x4*)&Kl[krow][kc4] = l4;
            const float* vs = vt + vd;
            s16x4 vv = {(short)f2bf(vs[0]), (short)f2bf(vs[D]),
                        (short)f2bf(vs[2 * D]), (short)f2bf(vs[3 * D])};
            *(s16x4*)&Vt[vd][vk] = vv;
        }
        __syncthreads();
        fx4 sacc = {0.f, 0.f, 0.f, 0.f};
        #pragma unroll
        for (int ks = 0; ks < 2; ++ks) {
            s16x8 kah = *(const s16x8*)&Kh[kkb * 16 + tq][ks * 32 + quad * 8];
            s16x8 kal = *(const s16x8*)&Kl[kkb * 16 + tq][ks * 32 + quad * 8];
            sacc = __builtin_amdgcn_mfma_f32_16x16x32_bf16(kah, qh[ks], sacc, 0, 0, 0);
            sacc = __builtin_amdgcn_mfma_f32_16x16x32_bf16(kah, ql[ks], sacc, 0, 0, 0);
            sacc = __builtin_amdgcn_mfma_f32_16x16x32_bf16(kal, qh[ks], sacc, 0, 0, 0);
        }
        s16x4 pp = {(short)f2bf(__expf(sacc[0])), (short)f2bf(__expf(sacc[1])),
                    (short)f2bf(__expf(sacc[2])), (short)f2bf(__expf(sacc[3]))};
        *(s16x4*)&Pf[mba * 16 + tq][kkb * 16 + (quad << 2)] = pp;
        __syncthreads();
        #pragma unroll
        for (int ks = 0; ks < 2; ++ks) {
            s16x8 pa = *(const s16x8*)&Pf[mba * 16 + tq][ks * 32 + quad * 8];
            const unsigned short* vr = &Vt[kkb * 16 + tq][ks * 32 + quad * 8];
            s16x4 va = *(const s16x4*)vr;
            s16x4 vb2 = *(const s16x4*)(vr + 4);
            s16x8 vfull = __builtin_shufflevector(va, vb2, 0, 1, 2, 3, 4, 5, 6, 7);
            oacc = __builtin_amdgcn_mfma_f32_16x16x32_bf16(pa, vfull, oacc, 0, 0, 0);
        }
    }
    #pragma unroll
    for (int r = 0; r < 4; ++r)
        ob[(size_t)(q0 + mba * 16 + quad * 4 + r) * D + kkb * 16 + tq] = oacc[r];
}

extern "C" void kernel_launch(void* const* d_in, const int* in_sizes, int n_in,
                              void* d_out, int out_size, void* d_ws, size_t ws_size,
                              hipStream_t stream) {
    const float* q = (const float*)d_in[0];
    const float* k = (const float*)d_in[1];
    const float* v = (const float*)d_in[2];
    float* out = (float*)d_out;
    const int nbatch = in_sizes[0] / (S * D);   // 4
    const size_t elems = (size_t)nbatch * S * D;

    // ws: kf (fp16, 2MB) | vf (bf16, 2MB) | partial[2] (fp32, 8MB) = 12MB
    const size_t need = elems * 2 * 2 + elems * 2 * 4;
    if (nbatch == 4 && ws_size >= need && d_ws != nullptr) {
        unsigned short* kf = (unsigned short*)d_ws;
        unsigned short* vf = kf + elems;
        float* partial = (float*)(vf + elems);

        prep2<<<nbatch * TILES * 2, 256, 0, stream>>>(k, v, kf, vf);
        dim3 grid(S / QROWS, nbatch, 2);
        attn_main4<<<grid, 512, 0, stream>>>(q, kf, vf, partial);
        const int n4 = (int)(elems / 4);
        reduce_out<<<(n4 + 255) / 256, 256, 0, stream>>>(
            (const float4*)partial, (const float4*)(partial + elems),
            (float4*)out, n4);
    } else {
        dim3 grid(S / 64, nbatch);
        attn_fallback<<<grid, 1024, 0, stream>>>(q, k, v, out);
    }
}